// Round 2
// baseline (638.974 us; speedup 1.0000x reference)
//
#include <hip/hip_runtime.h>

// Problem constants (fixed by reference)
#define Bb 2
#define Vv 16
#define Hh 512
#define Ww 512
#define Kk 64      // P*P
#define Ee 1024
#define Ll 4096    // (H/P)*(W/P)

typedef __bf16 bf16x8 __attribute__((ext_vector_type(8)));
typedef float f32x4 __attribute__((ext_vector_type(4)));

static __device__ __forceinline__ bf16x8 cvt8(float4 a, float4 b) {
    bf16x8 r = { (__bf16)a.x, (__bf16)a.y, (__bf16)a.z, (__bf16)a.w,
                 (__bf16)b.x, (__bf16)b.y, (__bf16)b.z, (__bf16)b.w };
    return r;
}

// Barrier-free, LDS-free patch-embed GEMM.
// Key observation: the MFMA fragments need 8 consecutive K elements per lane,
// and K index k = (r&7)*8 + q maps 8 consecutive k (k%8==0) to 8 consecutive
// pixels of one image row -> B-fragments load directly from x (32B/lane,
// coalesced). A-fragments are 8 consecutive floats of a weight row. So no
// LDS staging, no __syncthreads, no vmcnt(0) drain of the store stream.
//
// Grid: (mt, bv) = (32, 32). Each block: 128 L rows x full E=1024,
// looping 8 E-tiles of 128 with software-pipelined W prefetch.
// MFMA D layout: col=lane&15 -> L row, row=quad*4+reg -> 4 consecutive E cols
// => f32x4 nontemporal stores. Bias goes into the accumulator init (C-in).
__global__ __launch_bounds__(256) void patch_embed_kernel(
    const float* __restrict__ x, const int* __restrict__ vars,
    const float* __restrict__ pw, const float* __restrict__ pb,
    float* __restrict__ out)
{
    const int tid = threadIdx.x;
    const int mt  = blockIdx.x;           // 0..31  L tiles of 128
    const int bv  = blockIdx.y;           // 0..31  b*V+v
    const int v   = bv & (Vv - 1);
    const int var = vars[v];

    const int lane = tid & 63;
    const int wv   = tid >> 6;
    const int wE   = (wv >> 1) << 6;      // wave E offset (0/64)
    const int wL   = (wv & 1) << 6;       // wave L offset (0/64)
    const int ln   = lane & 15;
    const int quad = lane >> 4;

    // ---- hoist X fragments straight from global (read once per block) ----
    // patch l = wL + nj*16 + ln; image row = (wL>>3) + kh*4 + quad;
    // cols = (nj*16+ln)*8 .. +8  -> two consecutive float4s per fragment.
    bf16x8 xf[2][4];
    {
        const float* xb = x + ((size_t)bv * Hh + (size_t)mt * 16 + (wL >> 3) + quad) * Ww;
        #pragma unroll
        for (int kh = 0; kh < 2; kh++) {
            const float* xr = xb + (size_t)(kh * 4) * Ww;
            #pragma unroll
            for (int nj = 0; nj < 4; nj++) {
                const float4* p = (const float4*)(xr + (nj * 16 + ln) * 8);
                xf[kh][nj] = cvt8(p[0], p[1]);
            }
        }
    }

    // W row base for this lane: row = var*Ee + nt*128 + wE + mi*16 + ln,
    // k offset = kh*32 + quad*8 (8 consecutive floats = two float4s).
    const float* wb = pw + ((size_t)var * Ee + wE + ln) * Kk + quad * 8;
    const float* bb = pb + (size_t)var * Ee + wE + quad * 4;
    float* ob = out + (size_t)bv * Ll * Ee
                    + (size_t)(mt * 128 + wL + ln) * Ee + wE + quad * 4;

    // prologue: load tile 0's raw W
    float4 wraw[2][4][2];
    #pragma unroll
    for (int kh = 0; kh < 2; kh++)
        #pragma unroll
        for (int mi = 0; mi < 4; mi++) {
            const float4* p = (const float4*)(wb + (size_t)(mi * 16) * Kk + kh * 32);
            wraw[kh][mi][0] = p[0];
            wraw[kh][mi][1] = p[1];
        }

    #pragma unroll 1
    for (int nt = 0; nt < 8; nt++) {
        // convert current tile's W (frees wraw for the prefetch)
        bf16x8 wf[2][4];
        #pragma unroll
        for (int kh = 0; kh < 2; kh++)
            #pragma unroll
            for (int mi = 0; mi < 4; mi++)
                wf[kh][mi] = cvt8(wraw[kh][mi][0], wraw[kh][mi][1]);

        // bias load BEFORE the W prefetch so the pre-MFMA vmcnt wait does not
        // have to drain the prefetch (vmcnt retires in issue order).
        f32x4 acc[4][4];
        #pragma unroll
        for (int mi = 0; mi < 4; mi++) {
            float4 t = *(const float4*)(bb + nt * 128 + mi * 16);
            f32x4 bias = { t.x, t.y, t.z, t.w };
            #pragma unroll
            for (int nj = 0; nj < 4; nj++) acc[mi][nj] = bias;
        }

        // software pipeline: issue next tile's W loads, latency hides under
        // the 32 MFMAs + 16 stores below.
        if (nt < 7) {
            #pragma unroll
            for (int kh = 0; kh < 2; kh++)
                #pragma unroll
                for (int mi = 0; mi < 4; mi++) {
                    const float4* p = (const float4*)(wb + (size_t)((nt + 1) * 128 + mi * 16) * Kk + kh * 32);
                    wraw[kh][mi][0] = p[0];
                    wraw[kh][mi][1] = p[1];
                }
        }

        #pragma unroll
        for (int kh = 0; kh < 2; kh++)
            #pragma unroll
            for (int mi = 0; mi < 4; mi++)
                #pragma unroll
                for (int nj = 0; nj < 4; nj++)
                    acc[mi][nj] = __builtin_amdgcn_mfma_f32_16x16x32_bf16(
                        wf[kh][mi], xf[kh][nj], acc[mi][nj], 0, 0, 0);

        // nontemporal f32x4 stores (bias already in acc)
        #pragma unroll
        for (int nj = 0; nj < 4; nj++) {
            float* op = ob + (size_t)(nj * 16) * Ee + nt * 128;
            #pragma unroll
            for (int mi = 0; mi < 4; mi++)
                __builtin_nontemporal_store(acc[mi][nj], (f32x4*)(op + mi * 16));
        }
    }
}

extern "C" void kernel_launch(void* const* d_in, const int* in_sizes, int n_in,
                              void* d_out, int out_size, void* d_ws, size_t ws_size,
                              hipStream_t stream) {
    const float* x    = (const float*)d_in[0];
    const int*   vars = (const int*)d_in[1];
    const float* pw   = (const float*)d_in[2];
    const float* pb   = (const float*)d_in[3];
    float* out = (float*)d_out;
    dim3 grid(Ll / 128, Bb * Vv);   // 32 x 32 = 1024 blocks
    dim3 block(256);
    hipLaunchKernelGGL(patch_embed_kernel, grid, block, 0, stream,
                       x, vars, pw, pb, out);
}

// Round 3
// 624.528 us; speedup vs baseline: 1.0231x; 1.0231x over previous
//
#include <hip/hip_runtime.h>

// Problem constants (fixed by reference)
#define Bb 2
#define Vv 16
#define Hh 512
#define Ww 512
#define Kk 64      // P*P
#define Ee 1024
#define Ll 4096    // (H/P)*(W/P)

typedef __bf16 bf16x8 __attribute__((ext_vector_type(8)));
typedef float f32x4 __attribute__((ext_vector_type(4)));

static __device__ __forceinline__ bf16x8 cvt8(float4 a, float4 b) {
    bf16x8 r = { (__bf16)a.x, (__bf16)a.y, (__bf16)a.z, (__bf16)a.w,
                 (__bf16)b.x, (__bf16)b.y, (__bf16)b.z, (__bf16)b.w };
    return r;
}

// One-shot, LDS-free, barrier-free patch-embed GEMM tile.
//
// Structure lesson from the bench ladder: the 8192-block one-shot schedule
// (258us) beats the 1024-block 8-tile loop (296us) -- the kernel is
// latency-bound and block churn provides the overlap. So: keep one tile per
// block, but load MFMA fragments STRAIGHT from global (k = p*8+q means 8
// consecutive k == 8 consecutive pixels of one image row; a W fragment is 8
// consecutive floats of a weight row). No LDS, no __syncthreads, therefore
// no vmcnt(0)/lgkmcnt(0) drain anywhere in the block.
//
// x re-reads across the 8 nt-blocks of a slab are Infinity-Cache hits
// (x = 33.6 MB << 256 MiB, L3 is die-level shared across XCDs).
//
// MFMA: A=W (M=E), B=X (N=L). D layout: col=lane&15 -> L row,
// row=quad*4+reg -> 4 consecutive E cols => f32x4 nontemporal stores.
// Bias enters as the accumulator init (MFMA C-in), no epilogue adds.
__global__ __launch_bounds__(256) void patch_embed_kernel(
    const float* __restrict__ x, const int* __restrict__ vars,
    const float* __restrict__ pw, const float* __restrict__ pb,
    float* __restrict__ out)
{
    const int tid = threadIdx.x;
    const int nt  = blockIdx.x;           // 0..7   E tiles of 128
    const int mt  = blockIdx.y;           // 0..31  L tiles of 128
    const int bv  = blockIdx.z;           // 0..31  b*V+v
    const int var = vars[bv & (Vv - 1)];  // uniform -> s_load

    const int lane = tid & 63;
    const int wv   = tid >> 6;
    const int wE   = (wv >> 1) << 6;      // wave E offset (0/64)
    const int wL   = (wv & 1) << 6;       // wave L offset (0/64)
    const int ln   = lane & 15;
    const int quad = lane >> 4;

    // ---- X fragments direct from global ----
    // patch l = wL + nj*16 + ln; image row = (wL>>3) + kh*4 + quad;
    // cols = (nj*16+ln)*8 .. +8  -> two consecutive float4s per fragment.
    const float* xb = x + ((size_t)bv * Hh + (size_t)mt * 16 + (wL >> 3) + quad) * Ww;
    bf16x8 xf[2][4];
    #pragma unroll
    for (int kh = 0; kh < 2; kh++) {
        const float* xr = xb + (size_t)(kh * 4) * Ww;
        #pragma unroll
        for (int nj = 0; nj < 4; nj++) {
            const float4* p = (const float4*)(xr + (nj * 16 + ln) * 8);
            float4 a = p[0], b = p[1];
            xf[kh][nj] = cvt8(a, b);
        }
    }

    // ---- W fragments direct from global ----
    // row e = nt*128 + wE + mi*16 + ln; k = kh*32 + quad*8 (8 consecutive).
    const float* wb = pw + ((size_t)var * Ee + (size_t)nt * 128 + wE + ln) * Kk + quad * 8;
    bf16x8 wf[2][4];
    #pragma unroll
    for (int kh = 0; kh < 2; kh++) {
        #pragma unroll
        for (int mi = 0; mi < 4; mi++) {
            const float4* p = (const float4*)(wb + (size_t)(mi * 16) * Kk + kh * 32);
            float4 a = p[0], b = p[1];
            wf[kh][mi] = cvt8(a, b);
        }
    }

    // ---- bias -> accumulator init (C-in) ----
    const float* bb = pb + (size_t)var * Ee + nt * 128 + wE + quad * 4;
    f32x4 acc[4][4];
    #pragma unroll
    for (int mi = 0; mi < 4; mi++) {
        float4 t = *(const float4*)(bb + mi * 16);
        f32x4 bias = { t.x, t.y, t.z, t.w };
        #pragma unroll
        for (int nj = 0; nj < 4; nj++) acc[mi][nj] = bias;
    }

    // ---- 32 MFMAs ----
    #pragma unroll
    for (int kh = 0; kh < 2; kh++)
        #pragma unroll
        for (int mi = 0; mi < 4; mi++)
            #pragma unroll
            for (int nj = 0; nj < 4; nj++)
                acc[mi][nj] = __builtin_amdgcn_mfma_f32_16x16x32_bf16(
                    wf[kh][mi], xf[kh][nj], acc[mi][nj], 0, 0, 0);

    // ---- nontemporal f32x4 stores (bias already in acc) ----
    float* ob = out + (size_t)bv * Ll * Ee
                    + (size_t)(mt * 128 + wL + ln) * Ee
                    + (size_t)nt * 128 + wE + quad * 4;
    #pragma unroll
    for (int nj = 0; nj < 4; nj++) {
        float* op = ob + (size_t)(nj * 16) * Ee;
        #pragma unroll
        for (int mi = 0; mi < 4; mi++)
            __builtin_nontemporal_store(acc[mi][nj], (f32x4*)(op + mi * 16));
    }
}

extern "C" void kernel_launch(void* const* d_in, const int* in_sizes, int n_in,
                              void* d_out, int out_size, void* d_ws, size_t ws_size,
                              hipStream_t stream) {
    const float* x    = (const float*)d_in[0];
    const int*   vars = (const int*)d_in[1];
    const float* pw   = (const float*)d_in[2];
    const float* pb   = (const float*)d_in[3];
    float* out = (float*)d_out;
    dim3 grid(Ee / 128, Ll / 128, Bb * Vv);   // 8 x 32 x 32 = 8192 blocks
    dim3 block(256);
    hipLaunchKernelGGL(patch_embed_kernel, grid, block, 0, stream,
                       x, vars, pw, pb, out);
}